// Round 4
// baseline (1503.968 us; speedup 1.0000x reference)
//
#include <hip/hip_runtime.h>
#include <hip/hip_bf16.h>
#include <cstdint>

typedef __attribute__((ext_vector_type(8))) short short8;
typedef __attribute__((ext_vector_type(4))) float f32x4;

#define B_  2
#define S_  2048
#define D_  1024
#define H_  16
#define HD  64

static __device__ __forceinline__ float bf2f(unsigned int u16) {
    union { unsigned int i; float f; } v; v.i = u16 << 16; return v.f;
}
static __device__ __forceinline__ unsigned short f2bf(float f) {
    union { float f; unsigned int i; } v; v.f = f;
    unsigned int r = v.i + 0x7FFFu + ((v.i >> 16) & 1u);
    return (unsigned short)(r >> 16);
}
// pack two floats to bf16x2 (hi in top 16, lo in bottom), round-half-up
static __device__ __forceinline__ unsigned pack_bf16(float hi, float lo) {
    union { float f; unsigned u; } h, l;
    h.f = hi; l.f = lo;
    return __builtin_amdgcn_perm(h.u + 0x8000u, l.u + 0x8000u, 0x07060302);
}
static __device__ __forceinline__ void load_lds_16B(const unsigned short* g, unsigned short* l) {
    __builtin_amdgcn_global_load_lds(
        (const __attribute__((address_space(1))) unsigned int*)g,
        (__attribute__((address_space(3))) unsigned int*)l, 16, 0, 0);
}

// ---------------- fp32 -> bf16 conversion ----------------
__global__ void cvt_f32_bf16(const float* __restrict__ src,
                             unsigned short* __restrict__ dst, int n4) {
    int i = blockIdx.x * 256 + threadIdx.x;
    if (i >= n4) return;
    float4 f = ((const float4*)src)[i];
    uint2 o;
    o.x = (unsigned int)f2bf(f.x) | ((unsigned int)f2bf(f.y) << 16);
    o.y = (unsigned int)f2bf(f.z) | ((unsigned int)f2bf(f.w) << 16);
    ((uint2*)dst)[i] = o;
}

__global__ void cvt_w4(const float* __restrict__ w0, const float* __restrict__ w1,
                       const float* __restrict__ w2, const float* __restrict__ w3,
                       unsigned short* __restrict__ dst) {
    int bid = blockIdx.x;
    int wsel = bid >> 10;
    const float* s = wsel == 0 ? w0 : wsel == 1 ? w1 : wsel == 2 ? w2 : w3;
    int i = (bid & 1023) * 256 + threadIdx.x;
    float4 f = ((const float4*)s)[i];
    uint2 o;
    o.x = (unsigned int)f2bf(f.x) | ((unsigned int)f2bf(f.y) << 16);
    o.y = (unsigned int)f2bf(f.z) | ((unsigned int)f2bf(f.w) << 16);
    ((uint2*)dst)[(size_t)wsel * 262144 + i] = o;
}

// ---------------- fused QKV GEMM, 128x128 tile, transposed LDS slots -----
// q,k written to [B,H,S,hd]; v written TRANSPOSED to vt [B,H,hd,S].
__global__ __launch_bounds__(256) void qkv_gemm(
    const unsigned short* __restrict__ xbf,
    const unsigned short* __restrict__ wq,
    const unsigned short* __restrict__ wk,
    const unsigned short* __restrict__ wv,
    unsigned short* __restrict__ qb,
    unsigned short* __restrict__ kb,
    unsigned short* __restrict__ vt)
{
    __shared__ unsigned short As[8 * 512];   // 8 blocks x (64 lanes x 8)
    __shared__ unsigned short Bs[8 * 512];
    __shared__ unsigned short LT[64 * 140];  // V transpose buffer

    const int tid  = threadIdx.x;
    const int w    = tid >> 6, lane = tid & 63;
    const int l15  = lane & 15, quad = lane >> 4;
    const int wrow = (w >> 1) * 64, wcol = (w & 1) * 64;

    const int m0 = blockIdx.x * 128;
    const int nc = blockIdx.y * 128;
    const int sel = nc >> 10;
    const int n0 = nc & 1023;
    const unsigned short* __restrict__ W = sel == 0 ? wq : (sel == 1 ? wk : wv);

    // transposed staging: lane -> row (lane&15), colgroup (lane>>4)
    const int slr = lane & 15, scg = (lane >> 4) * 8;
    const unsigned short* ga = xbf + (size_t)(m0 + slr) * 1024 + scg;
    const unsigned short* gb = W   + (size_t)(n0 + slr) * 1024 + scg;

    f32x4 acc[4][4] = {};

    for (int k0 = 0; k0 < 1024; k0 += 32) {
        __syncthreads();
        load_lds_16B(ga + (size_t)(w * 16) * 1024 + k0,        As + w * 512);
        load_lds_16B(ga + (size_t)(64 + w * 16) * 1024 + k0,   As + (w + 4) * 512);
        load_lds_16B(gb + (size_t)(w * 16) * 1024 + k0,        Bs + w * 512);
        load_lds_16B(gb + (size_t)(64 + w * 16) * 1024 + k0,   Bs + (w + 4) * 512);
        __syncthreads();

        short8 a[4], b[4];
#pragma unroll
        for (int i = 0; i < 4; i++)
            a[i] = *(const short8*)&As[(((w >> 1) * 4 + i) * 64 + quad * 16 + l15) * 8];
#pragma unroll
        for (int j = 0; j < 4; j++)
            b[j] = *(const short8*)&Bs[(((w & 1) * 4 + j) * 64 + quad * 16 + l15) * 8];
#pragma unroll
        for (int i = 0; i < 4; i++)
#pragma unroll
            for (int j = 0; j < 4; j++)
                acc[i][j] = __builtin_amdgcn_mfma_f32_16x16x32_bf16(a[i], b[j], acc[i][j], 0, 0, 0);
    }

    if (sel != 2) {
        unsigned short* __restrict__ Out = sel == 0 ? qb : kb;
#pragma unroll
        for (int i = 0; i < 4; i++) {
#pragma unroll
            for (int r = 0; r < 4; r++) {
                int m = m0 + wrow + i * 16 + quad * 4 + r;
                int bb = m >> 11, s = m & 2047;
#pragma unroll
                for (int j = 0; j < 4; j++) {
                    int n = n0 + wcol + j * 16 + l15;
                    int h = n >> 6, d = n & 63;
                    Out[(((size_t)(bb * H_ + h) * S_) + s) * HD + d] = f2bf(acc[i][j][r]);
                }
            }
        }
    } else {
        // V: transpose via LDS, write vt[B,H,hd,S]
        const int bb = m0 >> 11, s0 = m0 & 2047;
#pragma unroll
        for (int nh = 0; nh < 2; nh++) {
            __syncthreads();
            if ((w & 1) == nh) {
#pragma unroll
                for (int i = 0; i < 4; i++)
#pragma unroll
                    for (int r = 0; r < 4; r++) {
                        int ml = wrow + i * 16 + quad * 4 + r;
#pragma unroll
                        for (int j = 0; j < 4; j++)
                            LT[(j * 16 + l15) * 140 + ml] = f2bf(acc[i][j][r]);
                    }
            }
            __syncthreads();
            int dloc = tid >> 2, mseg = tid & 3;
            int h = (n0 + nh * 64) >> 6;
            unsigned short* dst = vt + (((size_t)bb * H_ + h) * HD + dloc) * 2048 + s0 + mseg * 32;
            uint2 r0 = *(const uint2*)&LT[dloc * 140 + mseg * 32];
            uint2 r1 = *(const uint2*)&LT[dloc * 140 + mseg * 32 + 4];
            uint2 r2 = *(const uint2*)&LT[dloc * 140 + mseg * 32 + 8];
            uint2 r3 = *(const uint2*)&LT[dloc * 140 + mseg * 32 + 12];
            uint2 r4 = *(const uint2*)&LT[dloc * 140 + mseg * 32 + 16];
            uint2 r5 = *(const uint2*)&LT[dloc * 140 + mseg * 32 + 20];
            uint2 r6 = *(const uint2*)&LT[dloc * 140 + mseg * 32 + 24];
            uint2 r7 = *(const uint2*)&LT[dloc * 140 + mseg * 32 + 28];
            ((uint4*)dst)[0] = make_uint4(r0.x, r0.y, r1.x, r1.y);
            ((uint4*)dst)[1] = make_uint4(r2.x, r2.y, r3.x, r3.y);
            ((uint4*)dst)[2] = make_uint4(r4.x, r4.y, r5.x, r5.y);
            ((uint4*)dst)[3] = make_uint4(r6.x, r6.y, r7.x, r7.y);
        }
    }
}

// ---------------- output GEMM, transposed LDS slots ----------------------
__global__ __launch_bounds__(256) void out_gemm(
    const unsigned short* __restrict__ A,
    const unsigned short* __restrict__ Bt,
    float* __restrict__ C)
{
    __shared__ unsigned short As[8 * 512];
    __shared__ unsigned short Bs[8 * 512];

    const int tid  = threadIdx.x;
    const int w    = tid >> 6, lane = tid & 63;
    const int l15  = lane & 15, quad = lane >> 4;
    const int wrow = (w >> 1) * 64, wcol = (w & 1) * 64;

    const int m0 = blockIdx.x * 128;
    const int n0 = blockIdx.y * 128;

    const int slr = lane & 15, scg = (lane >> 4) * 8;
    const unsigned short* ga = A  + (size_t)(m0 + slr) * 1024 + scg;
    const unsigned short* gb = Bt + (size_t)(n0 + slr) * 1024 + scg;

    f32x4 acc[4][4] = {};

    for (int k0 = 0; k0 < 1024; k0 += 32) {
        __syncthreads();
        load_lds_16B(ga + (size_t)(w * 16) * 1024 + k0,        As + w * 512);
        load_lds_16B(ga + (size_t)(64 + w * 16) * 1024 + k0,   As + (w + 4) * 512);
        load_lds_16B(gb + (size_t)(w * 16) * 1024 + k0,        Bs + w * 512);
        load_lds_16B(gb + (size_t)(64 + w * 16) * 1024 + k0,   Bs + (w + 4) * 512);
        __syncthreads();

        short8 a[4], b[4];
#pragma unroll
        for (int i = 0; i < 4; i++)
            a[i] = *(const short8*)&As[(((w >> 1) * 4 + i) * 64 + quad * 16 + l15) * 8];
#pragma unroll
        for (int j = 0; j < 4; j++)
            b[j] = *(const short8*)&Bs[(((w & 1) * 4 + j) * 64 + quad * 16 + l15) * 8];
#pragma unroll
        for (int i = 0; i < 4; i++)
#pragma unroll
            for (int j = 0; j < 4; j++)
                acc[i][j] = __builtin_amdgcn_mfma_f32_16x16x32_bf16(a[i], b[j], acc[i][j], 0, 0, 0);
    }

#pragma unroll
    for (int i = 0; i < 4; i++)
#pragma unroll
        for (int r = 0; r < 4; r++) {
            int m = m0 + wrow + i * 16 + quad * 4 + r;
#pragma unroll
            for (int j = 0; j < 4; j++)
                C[(size_t)m * 1024 + n0 + wcol + j * 16 + l15] = acc[i][j][r];
        }
}

// ---------------- RoPE on K only ([B,H,S,hd] bf16, in place) -------------
__global__ void rope_k(unsigned short* __restrict__ kb,
                       const float* __restrict__ fcos,
                       const float* __restrict__ fsin)
{
    int idx = blockIdx.x * 256 + threadIdx.x;        // 2M pairs
    int t  = idx & 31;
    int s  = (idx >> 5) & (S_ - 1);
    int bh = idx >> 16;
    float c  = fcos[s * 32 + t];
    float si = fsin[s * 32 + t];
    size_t off = ((size_t)bh * S_ + s) * HD + 2 * t;
    unsigned int* kp = (unsigned int*)(kb + off);
    unsigned int u = *kp;
    float r = bf2f(u & 0xffffu), im = bf2f(u >> 16);
    *kp = pack_bf16(im * c + r * si, r * c - im * si);
}

// ---------------- causal flash attention -------------------------------
// block = 128 threads (2 waves), each wave owns 32 q rows (2 fragments).
// K via global_load_lds (transposed slots, conflict-free); V^T straight
// from global (vt); O accumulated transposed (O^T = V^T · P^T) so softmax
// stats sit at q = lane&15 with no rescale shuffles. Q-rope fused in-reg
// with 0.125*log2(e) folded in.
__global__ __launch_bounds__(128) void flash_attn_mfma(
    const unsigned short* __restrict__ qb,
    const unsigned short* __restrict__ kb,
    const unsigned short* __restrict__ vt,
    const float* __restrict__ fcos,
    const float* __restrict__ fsin,
    unsigned short* __restrict__ attnc)
{
    __shared__ unsigned short Ks[2 * 4 * 64 * 8];    // [kh][sub][slot][8]
    __shared__ unsigned short Pls[2][2][16][76];     // [wave][frag][q][64keys+pad]

    const int bh   = blockIdx.x;
    const int qt   = 31 - blockIdx.y;                // heavy blocks first
    const int b    = bh >> 4, h = bh & 15;
    const int tid  = threadIdx.x;
    const int w    = tid >> 6;
    const int lane = tid & 63;
    const int l15  = lane & 15;
    const int quad = lane >> 4;
    const size_t bhS = (size_t)bh * S_;

    // ---- load + rope + scale Q fragments (once) ----
    short8 qfrag[2][2];
    float mrow[2], lrow[2];
    const float SC = 0.125f * 1.44269504f;
#pragma unroll
    for (int f = 0; f < 2; f++) {
        int qrow = qt * 64 + w * 32 + f * 16 + l15;
        const unsigned short* qp = qb + (bhS + qrow) * HD;
#pragma unroll
        for (int kh = 0; kh < 2; kh++) {
            uint4 u = *(const uint4*)(qp + kh * 32 + quad * 8);
            float4 c4 = *(const float4*)&fcos[qrow * 32 + kh * 16 + quad * 4];
            float4 s4 = *(const float4*)&fsin[qrow * 32 + kh * 16 + quad * 4];
            unsigned uu[4] = {u.x, u.y, u.z, u.w};
            const float* cc = (const float*)&c4;
            const float* ss = (const float*)&s4;
            unsigned o[4];
#pragma unroll
            for (int p = 0; p < 4; p++) {
                float r  = bf2f(uu[p] & 0xffffu), im = bf2f(uu[p] >> 16);
                float c  = cc[p] * SC, si = ss[p] * SC;
                o[p] = pack_bf16(im * c + r * si, r * c - im * si);
            }
            union { uint4 u4; short8 s8; } cvt;
            cvt.u4 = make_uint4(o[0], o[1], o[2], o[3]);
            qfrag[f][kh] = cvt.s8;
        }
        mrow[f] = -INFINITY;
        lrow[f] = 0.0f;
    }

    f32x4 O[2][4] = {};     // O^T: (d = dt*16 + quad*4 + r, q = l15)
    const int klr = lane & 15, kcg = (lane >> 4) * 8;

    for (int jt = 0; jt <= qt; jt++) {
        const int j0 = jt * 64;
        // ---- stage K (transposed slots): wave w does subs w, w+2 ----
        {
            const unsigned short* ks = kb + (bhS + j0 + klr) * HD + kcg;
#pragma unroll
            for (int kh = 0; kh < 2; kh++) {
                load_lds_16B(ks + (size_t)(w * 16) * HD + kh * 32,
                             &Ks[((kh * 4 + w) * 64) * 8]);
                load_lds_16B(ks + (size_t)((w + 2) * 16) * HD + kh * 32,
                             &Ks[((kh * 4 + w + 2) * 64) * 8]);
            }
        }
        __syncthreads();

        // ---- prefetch V^T fragments from global (L2) ----
        short8 vf[2][4];
#pragma unroll
        for (int kg = 0; kg < 2; kg++)
#pragma unroll
            for (int dt = 0; dt < 4; dt++)
                vf[kg][dt] = *(const short8*)(vt
                    + ((size_t)bh * HD + dt * 16 + l15) * 2048
                    + j0 + kg * 32 + quad * 8);

        const bool diag   = (jt == qt);
        const int  nsub0  = diag ? (2 * w + 1) : 4;
        const int  maxsub = diag ? (2 * w + 2) : 4;
        const int  kgmax  = diag ? (w + 1) : 2;

        // ---- S^T = K · Q^T ----
        f32x4 Sacc[2][4];
        for (int sub = 0; sub < maxsub; sub++) {
            short8 kf0 = *(const short8*)&Ks[((0 * 4 + sub) * 64 + quad * 16 + l15) * 8];
            short8 kf1 = *(const short8*)&Ks[((1 * 4 + sub) * 64 + quad * 16 + l15) * 8];
            if (sub < nsub0) {
                f32x4 s = {};
                s = __builtin_amdgcn_mfma_f32_16x16x32_bf16(kf0, qfrag[0][0], s, 0, 0, 0);
                s = __builtin_amdgcn_mfma_f32_16x16x32_bf16(kf1, qfrag[0][1], s, 0, 0, 0);
                Sacc[0][sub] = s;
            }
            f32x4 s1 = {};
            s1 = __builtin_amdgcn_mfma_f32_16x16x32_bf16(kf0, qfrag[1][0], s1, 0, 0, 0);
            s1 = __builtin_amdgcn_mfma_f32_16x16x32_bf16(kf1, qfrag[1][1], s1, 0, 0, 0);
            Sacc[1][sub] = s1;
        }

        // ---- softmax per fragment ----
#pragma unroll
        for (int f = 0; f < 2; f++) {
            const int nsub = f ? maxsub : nsub0;
            float tmax = -INFINITY;
            for (int sub = 0; sub < nsub; sub++) {
                f32x4 s = Sacc[f][sub];
                if (diag && sub == nsub - 1) {
#pragma unroll
                    for (int r = 0; r < 4; r++)
                        if (4 * quad + r > l15) s[r] = -INFINITY;
                    Sacc[f][sub] = s;
                }
                tmax = fmaxf(tmax, fmaxf(fmaxf(s[0], s[1]), fmaxf(s[2], s[3])));
            }
            tmax = fmaxf(tmax, __shfl_xor(tmax, 16, 64));
            tmax = fmaxf(tmax, __shfl_xor(tmax, 32, 64));
            float mnew = fmaxf(mrow[f], tmax);
            float ccr  = __builtin_amdgcn_exp2f(mrow[f] - mnew);
            float psum = 0.0f;
            for (int sub = 0; sub < nsub; sub++) {
                f32x4 s = Sacc[f][sub];
                float p0 = __builtin_amdgcn_exp2f(s[0] - mnew);
                float p1 = __builtin_amdgcn_exp2f(s[1] - mnew);
                float p2 = __builtin_amdgcn_exp2f(s[2] - mnew);
                float p3 = __builtin_amdgcn_exp2f(s[3] - mnew);
                psum += (p0 + p1) + (p2 + p3);
                uint2 pk;
                pk.x = pack_bf16(p1, p0);
                pk.y = pack_bf16(p3, p2);
                *(uint2*)&Pls[w][f][l15][sub * 16 + quad * 4] = pk;
            }
            if (diag && f == 0) {
                uint2 z; z.x = 0u; z.y = 0u;
                *(uint2*)&Pls[w][0][l15][nsub0 * 16 + quad * 4] = z;
            }
            psum += __shfl_xor(psum, 16, 64);
            psum += __shfl_xor(psum, 32, 64);
            lrow[f] = lrow[f] * ccr + psum;
            mrow[f] = mnew;
#pragma unroll
            for (int dt = 0; dt < 4; dt++) {
                O[f][dt][0] *= ccr; O[f][dt][1] *= ccr;
                O[f][dt][2] *= ccr; O[f][dt][3] *= ccr;
            }
        }

        // ---- PV: O^T += V^T · P^T ----
        for (int kg = 0; kg < kgmax; kg++) {
#pragma unroll
            for (int f = 0; f < 2; f++) {
                uint2 pa = *(const uint2*)&Pls[w][f][l15][kg * 32 + quad * 8];
                uint2 pb = *(const uint2*)&Pls[w][f][l15][kg * 32 + quad * 8 + 4];
                union { uint4 u4; short8 s8; } cvt;
                cvt.u4 = make_uint4(pa.x, pa.y, pb.x, pb.y);
#pragma unroll
                for (int dt = 0; dt < 4; dt++)
                    O[f][dt] = __builtin_amdgcn_mfma_f32_16x16x32_bf16(vf[kg][dt], cvt.s8, O[f][dt], 0, 0, 0);
            }
        }
        __syncthreads();
    }

    // ---- epilogue ----
#pragma unroll
    for (int f = 0; f < 2; f++) {
        float inv = 1.0f / lrow[f];
        int qrow = qt * 64 + w * 32 + f * 16 + l15;
        unsigned short* op = attnc + (((size_t)b * S_ + qrow) * H_ + h) * HD;
#pragma unroll
        for (int dt = 0; dt < 4; dt++)
#pragma unroll
            for (int r = 0; r < 4; r++)
                op[dt * 16 + quad * 4 + r] = f2bf(O[f][dt][r] * inv);
    }
}

// ---------------- launch ----------------
extern "C" void kernel_launch(void* const* d_in, const int* in_sizes, int n_in,
                              void* d_out, int out_size, void* d_ws, size_t ws_size,
                              hipStream_t stream) {
    const float* x    = (const float*)d_in[0];
    const float* fcos = (const float*)d_in[1];
    const float* fsin = (const float*)d_in[2];
    const float* Wq   = (const float*)d_in[3];
    const float* Wk   = (const float*)d_in[4];
    const float* Wv   = (const float*)d_in[5];
    const float* Wo   = (const float*)d_in[6];
    float* out = (float*)d_out;

    unsigned short* ws = (unsigned short*)d_ws;
    unsigned short* xbf = ws;                      // 4M elems
    unsigned short* wqb = xbf + 4096 * 1024;       // 1M each, contiguous
    unsigned short* wkb = wqb + 1024 * 1024;
    unsigned short* wvb = wkb + 1024 * 1024;
    unsigned short* wob = wvb + 1024 * 1024;
    unsigned short* qb  = wob + 1024 * 1024;
    unsigned short* kb  = qb + 4096 * 1024;
    unsigned short* vt  = kb + 4096 * 1024;        // transposed V [B,H,hd,S]
    unsigned short* attnc = vt + 4096 * 1024;

    cvt_f32_bf16<<<4096, 256, 0, stream>>>(x, xbf, 4096 * 1024 / 4);
    cvt_w4<<<4096, 256, 0, stream>>>(Wq, Wk, Wv, Wo, wqb);

    qkv_gemm<<<dim3(32, 24), 256, 0, stream>>>(xbf, wqb, wkb, wvb, qb, kb, vt);

    rope_k<<<8192, 256, 0, stream>>>(kb, fcos, fsin);

    flash_attn_mfma<<<dim3(32, 32), 128, 0, stream>>>(qb, kb, vt, fcos, fsin, attnc);

    out_gemm<<<dim3(32, 8), 256, 0, stream>>>(attnc, wob, out);
}

// Round 5
// 257.209 us; speedup vs baseline: 5.8473x; 5.8473x over previous
//
#include <hip/hip_runtime.h>
#include <hip/hip_bf16.h>
#include <cstdint>

typedef __attribute__((ext_vector_type(8))) short short8;
typedef __attribute__((ext_vector_type(4))) float f32x4;

#define B_  2
#define S_  2048
#define D_  1024
#define H_  16
#define HD  64

static __device__ __forceinline__ float bf2f(unsigned int u16) {
    union { unsigned int i; float f; } v; v.i = u16 << 16; return v.f;
}
static __device__ __forceinline__ unsigned short f2bf(float f) {
    union { float f; unsigned int i; } v; v.f = f;
    unsigned int r = v.i + 0x7FFFu + ((v.i >> 16) & 1u);
    return (unsigned short)(r >> 16);
}
// pack two floats to bf16x2 (hi in top 16, lo in bottom), round-half-up
static __device__ __forceinline__ unsigned pack_bf16(float hi, float lo) {
    union { float f; unsigned u; } h, l;
    h.f = hi; l.f = lo;
    return __builtin_amdgcn_perm(h.u + 0x8000u, l.u + 0x8000u, 0x07060302);
}
static __device__ __forceinline__ void load_lds_16B(const unsigned short* g, unsigned short* l) {
    __builtin_amdgcn_global_load_lds(
        (const __attribute__((address_space(1))) unsigned int*)g,
        (__attribute__((address_space(3))) unsigned int*)l, 16, 0, 0);
}

// ---------------- fp32 -> bf16 conversion ----------------
__global__ void cvt_f32_bf16(const float* __restrict__ src,
                             unsigned short* __restrict__ dst, int n4) {
    int i = blockIdx.x * 256 + threadIdx.x;
    if (i >= n4) return;
    float4 f = ((const float4*)src)[i];
    uint2 o;
    o.x = (unsigned int)f2bf(f.x) | ((unsigned int)f2bf(f.y) << 16);
    o.y = (unsigned int)f2bf(f.z) | ((unsigned int)f2bf(f.w) << 16);
    ((uint2*)dst)[i] = o;
}

__global__ void cvt_w4(const float* __restrict__ w0, const float* __restrict__ w1,
                       const float* __restrict__ w2, const float* __restrict__ w3,
                       unsigned short* __restrict__ dst) {
    int bid = blockIdx.x;
    int wsel = bid >> 10;
    const float* s = wsel == 0 ? w0 : wsel == 1 ? w1 : wsel == 2 ? w2 : w3;
    int i = (bid & 1023) * 256 + threadIdx.x;
    float4 f = ((const float4*)s)[i];
    uint2 o;
    o.x = (unsigned int)f2bf(f.x) | ((unsigned int)f2bf(f.y) << 16);
    o.y = (unsigned int)f2bf(f.z) | ((unsigned int)f2bf(f.w) << 16);
    ((uint2*)dst)[(size_t)wsel * 262144 + i] = o;
}

// ---------------- fused QKV GEMM, 128x128 tile, transposed LDS slots -----
// q,k written to [B,H,S,hd]; v written TRANSPOSED to vt [B,H,hd,S].
__global__ __launch_bounds__(256) void qkv_gemm(
    const unsigned short* __restrict__ xbf,
    const unsigned short* __restrict__ wq,
    const unsigned short* __restrict__ wk,
    const unsigned short* __restrict__ wv,
    unsigned short* __restrict__ qb,
    unsigned short* __restrict__ kb,
    unsigned short* __restrict__ vt)
{
    __shared__ unsigned short As[8 * 512];
    __shared__ unsigned short Bs[8 * 512];
    __shared__ unsigned short LT[64 * 140];

    const int tid  = threadIdx.x;
    const int w    = tid >> 6, lane = tid & 63;
    const int l15  = lane & 15, quad = lane >> 4;
    const int wrow = (w >> 1) * 64, wcol = (w & 1) * 64;

    const int m0 = blockIdx.x * 128;
    const int nc = blockIdx.y * 128;
    const int sel = nc >> 10;
    const int n0 = nc & 1023;
    const unsigned short* __restrict__ W = sel == 0 ? wq : (sel == 1 ? wk : wv);

    const int slr = lane & 15, scg = (lane >> 4) * 8;
    const unsigned short* ga = xbf + (size_t)(m0 + slr) * 1024 + scg;
    const unsigned short* gb = W   + (size_t)(n0 + slr) * 1024 + scg;

    f32x4 acc[4][4] = {};

    for (int k0 = 0; k0 < 1024; k0 += 32) {
        __syncthreads();
        load_lds_16B(ga + (size_t)(w * 16) * 1024 + k0,        As + w * 512);
        load_lds_16B(ga + (size_t)(64 + w * 16) * 1024 + k0,   As + (w + 4) * 512);
        load_lds_16B(gb + (size_t)(w * 16) * 1024 + k0,        Bs + w * 512);
        load_lds_16B(gb + (size_t)(64 + w * 16) * 1024 + k0,   Bs + (w + 4) * 512);
        __syncthreads();

        short8 a[4], b[4];
#pragma unroll
        for (int i = 0; i < 4; i++)
            a[i] = *(const short8*)&As[(((w >> 1) * 4 + i) * 64 + quad * 16 + l15) * 8];
#pragma unroll
        for (int j = 0; j < 4; j++)
            b[j] = *(const short8*)&Bs[(((w & 1) * 4 + j) * 64 + quad * 16 + l15) * 8];
#pragma unroll
        for (int i = 0; i < 4; i++)
#pragma unroll
            for (int j = 0; j < 4; j++)
                acc[i][j] = __builtin_amdgcn_mfma_f32_16x16x32_bf16(a[i], b[j], acc[i][j], 0, 0, 0);
    }

    if (sel != 2) {
        unsigned short* __restrict__ Out = sel == 0 ? qb : kb;
#pragma unroll
        for (int i = 0; i < 4; i++) {
#pragma unroll
            for (int r = 0; r < 4; r++) {
                int m = m0 + wrow + i * 16 + quad * 4 + r;
                int bb = m >> 11, s = m & 2047;
#pragma unroll
                for (int j = 0; j < 4; j++) {
                    int n = n0 + wcol + j * 16 + l15;
                    int h = n >> 6, d = n & 63;
                    Out[(((size_t)(bb * H_ + h) * S_) + s) * HD + d] = f2bf(acc[i][j][r]);
                }
            }
        }
    } else {
        // V: transpose via LDS, write vt[B,H,hd,S]
        const int bb = m0 >> 11, s0 = m0 & 2047;
#pragma unroll
        for (int nh = 0; nh < 2; nh++) {
            __syncthreads();
            if ((w & 1) == nh) {
#pragma unroll
                for (int i = 0; i < 4; i++)
#pragma unroll
                    for (int r = 0; r < 4; r++) {
                        int ml = wrow + i * 16 + quad * 4 + r;
#pragma unroll
                        for (int j = 0; j < 4; j++)
                            LT[(j * 16 + l15) * 140 + ml] = f2bf(acc[i][j][r]);
                    }
            }
            __syncthreads();
            int dloc = tid >> 2, mseg = tid & 3;
            int h = (n0 + nh * 64) >> 6;
            unsigned short* dst = vt + (((size_t)bb * H_ + h) * HD + dloc) * 2048 + s0 + mseg * 32;
            uint2 r0 = *(const uint2*)&LT[dloc * 140 + mseg * 32];
            uint2 r1 = *(const uint2*)&LT[dloc * 140 + mseg * 32 + 4];
            uint2 r2 = *(const uint2*)&LT[dloc * 140 + mseg * 32 + 8];
            uint2 r3 = *(const uint2*)&LT[dloc * 140 + mseg * 32 + 12];
            uint2 r4 = *(const uint2*)&LT[dloc * 140 + mseg * 32 + 16];
            uint2 r5 = *(const uint2*)&LT[dloc * 140 + mseg * 32 + 20];
            uint2 r6 = *(const uint2*)&LT[dloc * 140 + mseg * 32 + 24];
            uint2 r7 = *(const uint2*)&LT[dloc * 140 + mseg * 32 + 28];
            ((uint4*)dst)[0] = make_uint4(r0.x, r0.y, r1.x, r1.y);
            ((uint4*)dst)[1] = make_uint4(r2.x, r2.y, r3.x, r3.y);
            ((uint4*)dst)[2] = make_uint4(r4.x, r4.y, r5.x, r5.y);
            ((uint4*)dst)[3] = make_uint4(r6.x, r6.y, r7.x, r7.y);
        }
    }
}

// ---------------- output GEMM, transposed LDS slots ----------------------
__global__ __launch_bounds__(256) void out_gemm(
    const unsigned short* __restrict__ A,
    const unsigned short* __restrict__ Bt,
    float* __restrict__ C)
{
    __shared__ unsigned short As[8 * 512];
    __shared__ unsigned short Bs[8 * 512];

    const int tid  = threadIdx.x;
    const int w    = tid >> 6, lane = tid & 63;
    const int l15  = lane & 15, quad = lane >> 4;
    const int wrow = (w >> 1) * 64, wcol = (w & 1) * 64;

    const int m0 = blockIdx.x * 128;
    const int n0 = blockIdx.y * 128;

    const int slr = lane & 15, scg = (lane >> 4) * 8;
    const unsigned short* ga = A  + (size_t)(m0 + slr) * 1024 + scg;
    const unsigned short* gb = Bt + (size_t)(n0 + slr) * 1024 + scg;

    f32x4 acc[4][4] = {};

    for (int k0 = 0; k0 < 1024; k0 += 32) {
        __syncthreads();
        load_lds_16B(ga + (size_t)(w * 16) * 1024 + k0,        As + w * 512);
        load_lds_16B(ga + (size_t)(64 + w * 16) * 1024 + k0,   As + (w + 4) * 512);
        load_lds_16B(gb + (size_t)(w * 16) * 1024 + k0,        Bs + w * 512);
        load_lds_16B(gb + (size_t)(64 + w * 16) * 1024 + k0,   Bs + (w + 4) * 512);
        __syncthreads();

        short8 a[4], b[4];
#pragma unroll
        for (int i = 0; i < 4; i++)
            a[i] = *(const short8*)&As[(((w >> 1) * 4 + i) * 64 + quad * 16 + l15) * 8];
#pragma unroll
        for (int j = 0; j < 4; j++)
            b[j] = *(const short8*)&Bs[(((w & 1) * 4 + j) * 64 + quad * 16 + l15) * 8];
#pragma unroll
        for (int i = 0; i < 4; i++)
#pragma unroll
            for (int j = 0; j < 4; j++)
                acc[i][j] = __builtin_amdgcn_mfma_f32_16x16x32_bf16(a[i], b[j], acc[i][j], 0, 0, 0);
    }

#pragma unroll
    for (int i = 0; i < 4; i++)
#pragma unroll
        for (int r = 0; r < 4; r++) {
            int m = m0 + wrow + i * 16 + quad * 4 + r;
#pragma unroll
            for (int j = 0; j < 4; j++)
                C[(size_t)m * 1024 + n0 + wcol + j * 16 + l15] = acc[i][j][r];
        }
}

// ---------------- RoPE on K only ([B,H,S,hd] bf16, in place) -------------
__global__ void rope_k(unsigned short* __restrict__ kb,
                       const float* __restrict__ fcos,
                       const float* __restrict__ fsin)
{
    int idx = blockIdx.x * 256 + threadIdx.x;
    int t  = idx & 31;
    int s  = (idx >> 5) & (S_ - 1);
    int bh = idx >> 16;
    float c  = fcos[s * 32 + t];
    float si = fsin[s * 32 + t];
    size_t off = ((size_t)bh * S_ + s) * HD + 2 * t;
    unsigned int* kp = (unsigned int*)(kb + off);
    unsigned int u = *kp;
    float r = bf2f(u & 0xffffu), im = bf2f(u >> 16);
    *kp = pack_bf16(im * c + r * si, r * c - im * si);
}

// ---------------- causal flash attention -------------------------------
// block = 128 (2 waves), wave owns 32 q rows (2 frags of 16).
// ALL register-array indices are compile-time constants (full unroll);
// the diagonal tile is peeled out of the main loop (static code both paths).
__global__ __launch_bounds__(128) void flash_attn_mfma(
    const unsigned short* __restrict__ qb,
    const unsigned short* __restrict__ kb,
    const unsigned short* __restrict__ vt,
    const float* __restrict__ fcos,
    const float* __restrict__ fsin,
    unsigned short* __restrict__ attnc)
{
    __shared__ unsigned short Ks[2 * 4 * 64 * 8];    // [kh][sub][slot][8]
    __shared__ unsigned short Pls[2][2][16][76];     // [wave][frag][q][64keys+pad]

    const int bh   = blockIdx.x;
    const int qt   = 31 - blockIdx.y;                // heavy blocks first
    const int b    = bh >> 4, h = bh & 15;
    const int tid  = threadIdx.x;
    const int w    = tid >> 6;
    const int lane = tid & 63;
    const int l15  = lane & 15;
    const int quad = lane >> 4;
    const size_t bhS = (size_t)bh * S_;

    // ---- load + rope + scale Q fragments (once) ----
    short8 qfrag[2][2];
    float mrow[2], lrow[2];
    const float SC = 0.125f * 1.44269504f;
#pragma unroll
    for (int f = 0; f < 2; f++) {
        int qrow = qt * 64 + w * 32 + f * 16 + l15;
        const unsigned short* qp = qb + (bhS + qrow) * HD;
#pragma unroll
        for (int kh = 0; kh < 2; kh++) {
            uint4 u = *(const uint4*)(qp + kh * 32 + quad * 8);
            float4 c4 = *(const float4*)&fcos[qrow * 32 + kh * 16 + quad * 4];
            float4 s4 = *(const float4*)&fsin[qrow * 32 + kh * 16 + quad * 4];
            unsigned uu[4] = {u.x, u.y, u.z, u.w};
            const float* cc = (const float*)&c4;
            const float* ss = (const float*)&s4;
            unsigned o[4];
#pragma unroll
            for (int p = 0; p < 4; p++) {
                float r  = bf2f(uu[p] & 0xffffu), im = bf2f(uu[p] >> 16);
                float c  = cc[p] * SC, si = ss[p] * SC;
                o[p] = pack_bf16(im * c + r * si, r * c - im * si);
            }
            union { uint4 u4; short8 s8; } cvt;
            cvt.u4 = make_uint4(o[0], o[1], o[2], o[3]);
            qfrag[f][kh] = cvt.s8;
        }
        mrow[f] = -INFINITY;
        lrow[f] = 0.0f;
    }

    f32x4 O[2][4] = {};     // O^T: (d = dt*16 + quad*4 + r, q = l15)
    const int klr = lane & 15, kcg = (lane >> 4) * 8;
    const unsigned short* vbase = vt + ((size_t)bh * HD + l15) * 2048;

    // ================= full tiles (jt < qt): fully static ================
    for (int jt = 0; jt < qt; jt++) {
        const int j0 = jt * 64;
        {
            const unsigned short* ks = kb + (bhS + j0 + klr) * HD + kcg;
#pragma unroll
            for (int kh = 0; kh < 2; kh++) {
                load_lds_16B(ks + (size_t)(w * 16) * HD + kh * 32,
                             &Ks[((kh * 4 + w) * 64) * 8]);
                load_lds_16B(ks + (size_t)((w + 2) * 16) * HD + kh * 32,
                             &Ks[((kh * 4 + w + 2) * 64) * 8]);
            }
        }
        __syncthreads();

        short8 vf[2][4];
#pragma unroll
        for (int kg = 0; kg < 2; kg++)
#pragma unroll
            for (int dt = 0; dt < 4; dt++)
                vf[kg][dt] = *(const short8*)(vbase + (size_t)(dt * 16) * 2048
                                              + j0 + kg * 32 + quad * 8);

        // ---- S^T = K·Q^T (static) ----
        f32x4 Sacc[2][4];
#pragma unroll
        for (int sub = 0; sub < 4; sub++) {
            short8 kf0 = *(const short8*)&Ks[((0 * 4 + sub) * 64 + quad * 16 + l15) * 8];
            short8 kf1 = *(const short8*)&Ks[((1 * 4 + sub) * 64 + quad * 16 + l15) * 8];
#pragma unroll
            for (int f = 0; f < 2; f++) {
                f32x4 s = {};
                s = __builtin_amdgcn_mfma_f32_16x16x32_bf16(kf0, qfrag[f][0], s, 0, 0, 0);
                s = __builtin_amdgcn_mfma_f32_16x16x32_bf16(kf1, qfrag[f][1], s, 0, 0, 0);
                Sacc[f][sub] = s;
            }
        }

        // ---- softmax (static, no masking) ----
#pragma unroll
        for (int f = 0; f < 2; f++) {
            float tmax = -INFINITY;
#pragma unroll
            for (int sub = 0; sub < 4; sub++) {
                f32x4 s = Sacc[f][sub];
                tmax = fmaxf(tmax, fmaxf(fmaxf(s[0], s[1]), fmaxf(s[2], s[3])));
            }
            tmax = fmaxf(tmax, __shfl_xor(tmax, 16, 64));
            tmax = fmaxf(tmax, __shfl_xor(tmax, 32, 64));
            float mnew = fmaxf(mrow[f], tmax);
            float ccr  = __builtin_amdgcn_exp2f(mrow[f] - mnew);
            float psum = 0.0f;
#pragma unroll
            for (int sub = 0; sub < 4; sub++) {
                f32x4 s = Sacc[f][sub];
                float p0 = __builtin_amdgcn_exp2f(s[0] - mnew);
                float p1 = __builtin_amdgcn_exp2f(s[1] - mnew);
                float p2 = __builtin_amdgcn_exp2f(s[2] - mnew);
                float p3 = __builtin_amdgcn_exp2f(s[3] - mnew);
                psum += (p0 + p1) + (p2 + p3);
                uint2 pk;
                pk.x = pack_bf16(p1, p0);
                pk.y = pack_bf16(p3, p2);
                *(uint2*)&Pls[w][f][l15][sub * 16 + quad * 4] = pk;
            }
            psum += __shfl_xor(psum, 16, 64);
            psum += __shfl_xor(psum, 32, 64);
            lrow[f] = lrow[f] * ccr + psum;
            mrow[f] = mnew;
#pragma unroll
            for (int dt = 0; dt < 4; dt++) {
                O[f][dt][0] *= ccr; O[f][dt][1] *= ccr;
                O[f][dt][2] *= ccr; O[f][dt][3] *= ccr;
            }
        }

        // ---- PV (static) ----
#pragma unroll
        for (int kg = 0; kg < 2; kg++)
#pragma unroll
            for (int f = 0; f < 2; f++) {
                uint2 pa = *(const uint2*)&Pls[w][f][l15][kg * 32 + quad * 8];
                uint2 pb = *(const uint2*)&Pls[w][f][l15][kg * 32 + quad * 8 + 4];
                union { uint4 u4; short8 s8; } cvt;
                cvt.u4 = make_uint4(pa.x, pa.y, pb.x, pb.y);
#pragma unroll
                for (int dt = 0; dt < 4; dt++)
                    O[f][dt] = __builtin_amdgcn_mfma_f32_16x16x32_bf16(vf[kg][dt], cvt.s8, O[f][dt], 0, 0, 0);
            }
        __syncthreads();
    }

    // ================= diagonal tile (jt == qt) ==========================
    {
        const int j0 = qt * 64;
        {
            const unsigned short* ks = kb + (bhS + j0 + klr) * HD + kcg;
#pragma unroll
            for (int kh = 0; kh < 2; kh++) {
                load_lds_16B(ks + (size_t)(w * 16) * HD + kh * 32,
                             &Ks[((kh * 4 + w) * 64) * 8]);
                load_lds_16B(ks + (size_t)((w + 2) * 16) * HD + kh * 32,
                             &Ks[((kh * 4 + w + 2) * 64) * 8]);
            }
        }
        __syncthreads();

        short8 vf[2][4];
#pragma unroll
        for (int kg = 0; kg < 2; kg++)
            if (kg <= w)
#pragma unroll
                for (int dt = 0; dt < 4; dt++)
                    vf[kg][dt] = *(const short8*)(vbase + (size_t)(dt * 16) * 2048
                                                  + j0 + kg * 32 + quad * 8);

        // S with wave-uniform sub guards; lastsub per frag = 2*w + f
        f32x4 Sacc[2][4];
#pragma unroll
        for (int sub = 0; sub < 4; sub++) {
            if (sub <= 2 * w + 1) {
                short8 kf0 = *(const short8*)&Ks[((0 * 4 + sub) * 64 + quad * 16 + l15) * 8];
                short8 kf1 = *(const short8*)&Ks[((1 * 4 + sub) * 64 + quad * 16 + l15) * 8];
#pragma unroll
                for (int f = 0; f < 2; f++) {
                    if (sub <= 2 * w + f) {
                        f32x4 s = {};
                        s = __builtin_amdgcn_mfma_f32_16x16x32_bf16(kf0, qfrag[f][0], s, 0, 0, 0);
                        s = __builtin_amdgcn_mfma_f32_16x16x32_bf16(kf1, qfrag[f][1], s, 0, 0, 0);
                        Sacc[f][sub] = s;
                    }
                }
            }
        }

#pragma unroll
        for (int f = 0; f < 2; f++) {
            const int lastsub = 2 * w + f;
            float tmax = -INFINITY;
#pragma unroll
            for (int sub = 0; sub < 4; sub++) {
                if (sub <= lastsub) {
                    f32x4 s = Sacc[f][sub];
                    if (sub == lastsub) {
#pragma unroll
                        for (int r = 0; r < 4; r++)
                            if (4 * quad + r > l15) s[r] = -INFINITY;
                        Sacc[f][sub] = s;
                    }
                    tmax = fmaxf(tmax, fmaxf(fmaxf(s[0], s[1]), fmaxf(s[2], s[3])));
                }
            }
            tmax = fmaxf(tmax, __shfl_xor(tmax, 16, 64));
            tmax = fmaxf(tmax, __shfl_xor(tmax, 32, 64));
            float mnew = fmaxf(mrow[f], tmax);
            float ccr  = __builtin_amdgcn_exp2f(mrow[f] - mnew);
            float psum = 0.0f;
#pragma unroll
            for (int sub = 0; sub < 4; sub++) {
                if (sub <= lastsub) {
                    f32x4 s = Sacc[f][sub];
                    float p0 = __builtin_amdgcn_exp2f(s[0] - mnew);
                    float p1 = __builtin_amdgcn_exp2f(s[1] - mnew);
                    float p2 = __builtin_amdgcn_exp2f(s[2] - mnew);
                    float p3 = __builtin_amdgcn_exp2f(s[3] - mnew);
                    psum += (p0 + p1) + (p2 + p3);
                    uint2 pk;
                    pk.x = pack_bf16(p1, p0);
                    pk.y = pack_bf16(p3, p2);
                    *(uint2*)&Pls[w][f][l15][sub * 16 + quad * 4] = pk;
                }
            }
            if (f == 0) {   // zero-fill the odd partner sub for PV pairing
                uint2 z; z.x = 0u; z.y = 0u;
                *(uint2*)&Pls[w][0][l15][(2 * w + 1) * 16 + quad * 4] = z;
            }
            psum += __shfl_xor(psum, 16, 64);
            psum += __shfl_xor(psum, 32, 64);
            lrow[f] = lrow[f] * ccr + psum;
            mrow[f] = mnew;
#pragma unroll
            for (int dt = 0; dt < 4; dt++) {
                O[f][dt][0] *= ccr; O[f][dt][1] *= ccr;
                O[f][dt][2] *= ccr; O[f][dt][3] *= ccr;
            }
        }

#pragma unroll
        for (int kg = 0; kg < 2; kg++) {
            if (kg <= w) {
#pragma unroll
                for (int f = 0; f < 2; f++) {
                    uint2 pa = *(const uint2*)&Pls[w][f][l15][kg * 32 + quad * 8];
                    uint2 pb = *(const uint2*)&Pls[w][f][l15][kg * 32 + quad * 8 + 4];
                    union { uint4 u4; short8 s8; } cvt;
                    cvt.u4 = make_uint4(pa.x, pa.y, pb.x, pb.y);
#pragma unroll
                    for (int dt = 0; dt < 4; dt++)
                        O[f][dt] = __builtin_amdgcn_mfma_f32_16x16x32_bf16(vf[kg][dt], cvt.s8, O[f][dt], 0, 0, 0);
                }
            }
        }
    }

    // ---- epilogue ----
#pragma unroll
    for (int f = 0; f < 2; f++) {
        float inv = 1.0f / lrow[f];
        int qrow = qt * 64 + w * 32 + f * 16 + l15;
        unsigned short* op = attnc + (((size_t)b * S_ + qrow) * H_ + h) * HD;
#pragma unroll
        for (int dt = 0; dt < 4; dt++)
#pragma unroll
            for (int r = 0; r < 4; r++)
                op[dt * 16 + quad * 4 + r] = f2bf(O[f][dt][r] * inv);
    }
}

// ---------------- launch ----------------
extern "C" void kernel_launch(void* const* d_in, const int* in_sizes, int n_in,
                              void* d_out, int out_size, void* d_ws, size_t ws_size,
                              hipStream_t stream) {
    const float* x    = (const float*)d_in[0];
    const float* fcos = (const float*)d_in[1];
    const float* fsin = (const float*)d_in[2];
    const float* Wq   = (const float*)d_in[3];
    const float* Wk   = (const float*)d_in[4];
    const float* Wv   = (const float*)d_in[5];
    const float* Wo   = (const float*)d_in[6];
    float* out = (float*)d_out;

    unsigned short* ws = (unsigned short*)d_ws;
    unsigned short* xbf = ws;
    unsigned short* wqb = xbf + 4096 * 1024;
    unsigned short* wkb = wqb + 1024 * 1024;
    unsigned short* wvb = wkb + 1024 * 1024;
    unsigned short* wob = wvb + 1024 * 1024;
    unsigned short* qb  = wob + 1024 * 1024;
    unsigned short* kb  = qb + 4096 * 1024;
    unsigned short* vt  = kb + 4096 * 1024;        // transposed V [B,H,hd,S]
    unsigned short* attnc = vt + 4096 * 1024;

    cvt_f32_bf16<<<4096, 256, 0, stream>>>(x, xbf, 4096 * 1024 / 4);
    cvt_w4<<<4096, 256, 0, stream>>>(Wq, Wk, Wv, Wo, wqb);

    qkv_gemm<<<dim3(32, 24), 256, 0, stream>>>(xbf, wqb, wkb, wvb, qb, kb, vt);

    rope_k<<<8192, 256, 0, stream>>>(kb, fcos, fsin);

    flash_attn_mfma<<<dim3(32, 32), 128, 0, stream>>>(qb, kb, vt, fcos, fsin, attnc);

    out_gemm<<<dim3(32, 8), 256, 0, stream>>>(attnc, wob, out);
}